// Round 8
// baseline (452.372 us; speedup 1.0000x reference)
//
#include <hip/hip_runtime.h>
#include <cstdint>
#include <cstddef>

// ---------------------------------------------------------------------------
// NN_each_LN_exp: 33x33 SAME convs on 32x32 maps = dense 1024x1024 linear
// operators -> f16 MFMA GEMMs with fused epilogues. Row layout r = n*4+k:
// the 16x16x32 MFMA acc quad holds all 4 colors of one (n,o) cell.
// R8: depth kernel software-pipelined: NC/s global loads for K-step kb+1
// issue before the MFMA block of step kb (latency hidden under MFMA);
// launch_bounds(256,2) restores register headroom (R7's (256,4) squeezed the
// allocator and serialized the staging chain -> 74us vs R2's 59us).
// Lsel in f16. Phase A unchanged (101us, ~15% off its m97-rate floor).
// ---------------------------------------------------------------------------

typedef _Float16 f16;
typedef __attribute__((ext_vector_type(8))) _Float16 f16x8;
typedef __attribute__((ext_vector_type(4))) float f32x4;

#define NB   4096
#define PIX  1024
#define MR   (NB * 4)

__device__ __forceinline__ void gld_lds16(const void* g, void* l) {
    __builtin_amdgcn_global_load_lds(
        (const __attribute__((address_space(1))) void*)g,
        (__attribute__((address_space(3))) void*)l, 16, 0, 0);
}

// Conv matrices (1024x1024 f16): M[o][in] = w[a-i+16][b-j+16]
__global__ void build_mats(const float* __restrict__ we, const float* __restrict__ wn,
                           const float* __restrict__ wn2, const float* __restrict__ wem,
                           f16* __restrict__ Me, f16* __restrict__ Mn,
                           f16* __restrict__ Mn2, f16* __restrict__ Mem) {
    int idx = blockIdx.x * 256 + threadIdx.x;
    int o = idx >> 10, in = idx & 1023;
    int i = o >> 5, j = o & 31, a = in >> 5, b = in & 31;
    int u = a - i + 16, v = b - j + 16;
    bool ok = (u >= 0) && (u < 33) && (v >= 0) && (v < 33);
    int w = u * 33 + v;
    float ve = 0.f, vn = 0.f, vn2 = 0.f, vem = 0.f;
    if (ok) { ve = we[w]; vn = wn[w]; vn2 = wn2[w]; vem = wem[w]; }
    Me[idx]  = (f16)ve;
    Mn[idx]  = (f16)vn;
    Mn2[idx] = (f16)vn2;
    Mem[idx] = (f16)vem;
}

// W1 (100,1024) fp32 -> padded (128,1024) f16
__global__ void build_w1(const float* __restrict__ W1, f16* __restrict__ W1b) {
    int idx = blockIdx.x * 256 + threadIdx.x;
    int j = idx >> 10, i = idx & 1023;
    W1b[idx] = (f16)(j < 100 ? W1[j * 1024 + i] : 0.f);
}

// dots (34,32,4096) int32, (v,h,b) -> board[n*1024+p] bytes, LDS transpose
__global__ void build_board(const int* __restrict__ dots, unsigned char* __restrict__ board) {
    __shared__ unsigned char tile[64][68];
    int t = threadIdx.x;
    int bp = blockIdx.x & 15, bn = blockIdx.x >> 4;
    int p0 = bp * 64, n0 = bn * 64;
    int ln = t & 63, lp = t >> 6;
#pragma unroll
    for (int j = 0; j < 16; j++) {
        int p = lp * 16 + j;
        tile[p][ln] = (unsigned char)dots[(size_t)(p0 + p) * 4096 + n0 + ln];
    }
    __syncthreads();
#pragma unroll
    for (int j = 0; j < 16; j++) {
        int n = lp * 16 + j;
        board[(size_t)(n0 + n) * 1024 + p0 + ln] = tile[ln][n];
    }
}

// L0 = S1sel + En - NC_sel (gather); Sa = sigmoid(L0)
__global__ void mk_sa(const f16* __restrict__ S1sel, const f16* __restrict__ En,
                      const f16* __restrict__ NC,
                      const unsigned char* __restrict__ board,
                      f16* __restrict__ Lsel, f16* __restrict__ Sa) {
    int idx = blockIdx.x * 256 + threadIdx.x;      // n*1024+o
    int n = idx >> 10, o = idx & 1023;
    int c = board[idx];
    float L = 0.f;
    if (c > 0) {
        float ncsel = (float)NC[(size_t)(4 * n + c - 1) * 1024 + o];
        L = (float)S1sel[idx] + (float)En[idx] - ncsel;
    }
    Lsel[idx] = (f16)L;
    Sa[idx] = (f16)(1.f / (1.f + __expf(-L)));
}

// ---------------------------------------------------------------------------
// Generic GEMM body (phase A / MLP): BM=BN=128, BK=64, 4 waves as 2x2,
// 16x16x32 MFMA, XOR-swizzled chunks (conflict-free frag reads).
// ASRC: 0 direct async  2 each(board)  3 notm(board)  4 empty(board)
// MODE: 0 f16-out ldo   1 S1sel-select   5 f32 leaky
// ---------------------------------------------------------------------------
template <int MODE, int ASRC>
__device__ __forceinline__ void run_gemm(
    int bjob, int ypx, int nx, char* smem,
    const f16* __restrict__ X, const f16* __restrict__ B,
    const unsigned char* __restrict__ board,
    f16* __restrict__ outB, int ldo, float* __restrict__ outF) {
    char* smB = smem;                              // 16 KB
    char* smA = smem + 16384;

    const int tid = threadIdx.x;
    const int wv = tid >> 6, ln = tid & 63;
    const int wm = wv >> 1, wn_ = wv & 1;
    const int lr = ln & 15, lq = ln >> 4;

    int xcd = bjob & 7, slot = bjob >> 3;
    int bx = slot % nx;
    int by = xcd * ypx + slot / nx;
    const int rtile = by * 128, otile = bx * 128;
    const int img0 = (ASRC == 4) ? rtile : (rtile >> 2);

    const f32x4 fz = {0.f, 0.f, 0.f, 0.f};
    f32x4 acc[4][4];
#pragma unroll
    for (int i = 0; i < 4; i++)
#pragma unroll
        for (int j = 0; j < 4; j++) acc[i][j] = fz;

    for (int kb = 0; kb < 1024; kb += 64) {
#pragma unroll
        for (int t = 0; t < 4; t++) {              // B: async
            int c = (wv * 4 + t) * 64 + ln;
            int row = c >> 3, gcol = (c & 7) ^ (row & 7);
            gld_lds16(B + (size_t)(otile + row) * 1024 + kb + gcol * 8, smB + c * 16);
        }
        if (ASRC == 0) {
#pragma unroll
            for (int t = 0; t < 4; t++) {
                int c = (wv * 4 + t) * 64 + ln;
                int row = c >> 3, gcol = (c & 7) ^ (row & 7);
                gld_lds16(X + (size_t)(rtile + row) * 1024 + kb + gcol * 8, smA + c * 16);
            }
        } else if (ASRC == 4) {                    // board: 128 maps = 512 slots
#pragma unroll
            for (int t = 0; t < 2; t++) {
                int c = t * 256 + wv * 64 + ln;
                int row = c >> 2, g = (c & 3) ^ (row & 3);
                gld_lds16(board + (size_t)(img0 + row) * 1024 + kb + g * 16, smA + c * 16);
            }
        } else {                                   // ASRC 2/3: 32 maps = 128 slots
            if (wv < 2) {
                int c = wv * 64 + ln;
                int row = c >> 2, g = (c & 3) ^ (row & 3);
                gld_lds16(board + (size_t)(img0 + row) * 1024 + kb + g * 16, smA + c * 16);
            }
        }
        __syncthreads();

#pragma unroll
        for (int kk = 0; kk < 2; kk++) {
            const int oct = kk * 4 + lq;
            f16x8 af[4], bfr[4];
#pragma unroll
            for (int i = 0; i < 4; i++) {
                int rrow = wm * 64 + i * 16 + lr;
                if (ASRC == 0) {
                    af[i] = *(const f16x8*)(smA + rrow * 128 + (oct ^ (rrow & 7)) * 16);
                } else {
                    int m = (ASRC == 4) ? rrow : (rrow >> 2);
                    int k1 = (rrow & 3) + 1;
                    uint64_t bb = *(const uint64_t*)(smA + m * 64 +
                                    ((oct >> 1) ^ (m & 3)) * 16 + (oct & 1) * 8);
                    f16x8 v;
#pragma unroll
                    for (int jj = 0; jj < 8; jj++) {
                        int bj = (int)((bb >> (8 * jj)) & 0xff);
                        bool on = (ASRC == 2) ? (bj == k1)
                                : (ASRC == 3) ? (bj != 0 && bj != k1)
                                              : (bj == 0);
                        v[jj] = on ? (f16)1.f : (f16)0.f;
                    }
                    af[i] = v;
                }
            }
#pragma unroll
            for (int j = 0; j < 4; j++) {
                int brow = wn_ * 64 + j * 16 + lr;
                bfr[j] = *(const f16x8*)(smB + brow * 128 + (oct ^ (brow & 7)) * 16);
            }
#pragma unroll
            for (int i = 0; i < 4; i++)
#pragma unroll
                for (int j = 0; j < 4; j++)
                    acc[i][j] = __builtin_amdgcn_mfma_f32_16x16x32_f16(
                        af[i], bfr[j], acc[i][j], 0, 0, 0);
        }
        __syncthreads();
    }

#pragma unroll
    for (int i = 0; i < 4; i++) {
        int rbase = rtile + wm * 64 + i * 16 + lq * 4;
#pragma unroll
        for (int j = 0; j < 4; j++) {
            int o = otile + wn_ * 64 + j * 16 + lr;
            f32x4 a = acc[i][j];
            if (MODE == 0) {
#pragma unroll
                for (int v = 0; v < 4; v++)
                    outB[(size_t)(rbase + v) * ldo + o] = (f16)a[v];
            } else if (MODE == 5) {
#pragma unroll
                for (int v = 0; v < 4; v++) {
                    float x = a[v];
                    outF[(size_t)(rbase + v) * ldo + o] = x > 0.f ? x : 0.2f * x;
                }
            } else {                               // 1: selected color only
                int n = rbase >> 2;
                size_t no = (size_t)n * PIX + o;
                int c = board[no];
                float asel = (c == 1) ? a[0] : (c == 2) ? a[1] : (c == 3) ? a[2] : a[3];
                outB[no] = (f16)asel;
            }
        }
    }
}

// Phase A: [0,1024) stage1-sel, [1024,2048) NC, [2048,2304) En
__global__ void __launch_bounds__(256, 4) gemm_fa(
    const f16* __restrict__ Me, const f16* __restrict__ Mn,
    const f16* __restrict__ Mem, const unsigned char* __restrict__ board,
    f16* __restrict__ S1sel, f16* __restrict__ NC, f16* __restrict__ En) {
    __shared__ __attribute__((aligned(16))) char smem[24576];
    int bi = blockIdx.x;
    if (bi < 1024) {
        run_gemm<1, 2>(bi, 16, 8, smem, nullptr, Me, board, S1sel, 0, nullptr);
    } else if (bi < 2048) {
        run_gemm<0, 3>(bi - 1024, 16, 8, smem, nullptr, Mn, board, NC, PIX, nullptr);
    } else {
        run_gemm<0, 4>(bi - 2048, 4, 8, smem, nullptr, Mem, board, En, PIX, nullptr);
    }
}

// ---------------------------------------------------------------------------
// Depth GEMM, software-pipelined A-production:
//   pNC/pS regs hold NC/s for step kb; product ds_written at top of iter;
//   prefetch for kb+64 issues after barrier1, BEFORE the MFMA block, so the
//   global latency hides under MFMA. launch_bounds(256,2) for reg headroom.
// MODE 3: update Lsel(f16), write s.  MODE 4: write feat only.
// ---------------------------------------------------------------------------
template <int MODE>
__global__ void __launch_bounds__(256, 2) gemm_depth(
    const f16* __restrict__ Mn2, const unsigned char* __restrict__ board,
    const f16* __restrict__ NCs, const f16* __restrict__ Sin,
    const f16* __restrict__ En, f16* __restrict__ Lsel,
    f16* __restrict__ outB) {
    __shared__ __attribute__((aligned(16))) char smem[32768];
    char* smB = smem;
    char* smA = smem + 16384;

    const int tid = threadIdx.x;
    const int wv = tid >> 6, ln = tid & 63;
    const int wm = wv >> 1, wn_ = wv & 1;
    const int lr = ln & 15, lq = ln >> 4;

    int bi = blockIdx.x;
    int xcd = bi & 7, slot = bi >> 3;
    int bx = slot & 7;
    int by = xcd * 16 + (slot >> 3);
    const int rtile = by * 128, otile = bx * 128;

    // per-lane global addresses for the 4 A-chunks (advance by 64 f16 per step)
    const f16* ncp[4];
    const f16* sp[4];
#pragma unroll
    for (int t = 0; t < 4; t++) {
        int c = (wv * 4 + t) * 64 + ln;
        int row = c >> 3, gcol = (c & 7) ^ (row & 7);
        int gr = rtile + row;
        ncp[t] = NCs + (size_t)gr * 1024 + gcol * 8;
        sp[t]  = Sin + (size_t)(gr >> 2) * 1024 + gcol * 8;
    }

    const f32x4 fz = {0.f, 0.f, 0.f, 0.f};
    f32x4 acc[4][4];
#pragma unroll
    for (int i = 0; i < 4; i++)
#pragma unroll
        for (int j = 0; j < 4; j++) acc[i][j] = fz;

    f16x8 pNC[4], pS[4];
#pragma unroll
    for (int t = 0; t < 4; t++) {                  // prefetch kb=0
        pNC[t] = *(const f16x8*)(ncp[t]);
        pS[t]  = *(const f16x8*)(sp[t]);
    }

    for (int kb = 0; kb < 1024; kb += 64) {
        // ---- write A product for current step; stage B async ----
#pragma unroll
        for (int t = 0; t < 4; t++) {
            int c = (wv * 4 + t) * 64 + ln;
            *(f16x8*)(smA + c * 16) = pNC[t] * pS[t];
        }
#pragma unroll
        for (int t = 0; t < 4; t++) {
            int c = (wv * 4 + t) * 64 + ln;
            int row = c >> 3, gcol = (c & 7) ^ (row & 7);
            gld_lds16(Mn2 + (size_t)(otile + row) * 1024 + kb + gcol * 8, smB + c * 16);
        }
        __syncthreads();

        // ---- prefetch next step's NC/s (latency hides under MFMA) ----
        if (kb + 64 < 1024) {
#pragma unroll
            for (int t = 0; t < 4; t++) {
                pNC[t] = *(const f16x8*)(ncp[t] + kb + 64);
                pS[t]  = *(const f16x8*)(sp[t] + kb + 64);
            }
        }

        // ---- compute ----
#pragma unroll
        for (int kk = 0; kk < 2; kk++) {
            const int oct = kk * 4 + lq;
            f16x8 af[4], bfr[4];
#pragma unroll
            for (int i = 0; i < 4; i++) {
                int rrow = wm * 64 + i * 16 + lr;
                af[i] = *(const f16x8*)(smA + rrow * 128 + (oct ^ (rrow & 7)) * 16);
            }
#pragma unroll
            for (int j = 0; j < 4; j++) {
                int brow = wn_ * 64 + j * 16 + lr;
                bfr[j] = *(const f16x8*)(smB + brow * 128 + (oct ^ (brow & 7)) * 16);
            }
#pragma unroll
            for (int i = 0; i < 4; i++)
#pragma unroll
                for (int j = 0; j < 4; j++)
                    acc[i][j] = __builtin_amdgcn_mfma_f32_16x16x32_f16(
                        af[i], bfr[j], acc[i][j], 0, 0, 0);
        }
        __syncthreads();
    }

    // ---- epilogue ----
#pragma unroll
    for (int i = 0; i < 4; i++) {
        int rbase = rtile + wm * 64 + i * 16 + lq * 4;
#pragma unroll
        for (int j = 0; j < 4; j++) {
            int o = otile + wn_ * 64 + j * 16 + lr;
            f32x4 a = acc[i][j];
            int n = rbase >> 2;
            size_t no = (size_t)n * PIX + o;
            int c = board[no];
            float asel = (c == 1) ? a[0] : (c == 2) ? a[1] : (c == 3) ? a[2] : a[3];
            float E = (float)En[no];
            float Lnew = (c > 0) ? ((float)Lsel[no] + E + asel) : 0.f;
            float s = 1.f / (1.f + __expf(-Lnew));
            if (MODE != 4) Lsel[no] = (f16)Lnew;
            outB[no] = (f16)s;
        }
    }
}

// MLP layer 1: X1 = leaky(feat @ W1b^T), N=128
__global__ void __launch_bounds__(256, 4) gemm_mlp(
    const f16* __restrict__ feat, const f16* __restrict__ W1b,
    float* __restrict__ X1) {
    __shared__ __attribute__((aligned(16))) char smem[32768];
    run_gemm<5, 0>(blockIdx.x, 4, 1, smem, feat, W1b, nullptr, nullptr, 128, X1);
}

// MLP layers 2+3
__global__ void __launch_bounds__(256) mlp23(const float* __restrict__ X1,
                                             const float* __restrict__ W2,
                                             const float* __restrict__ W3,
                                             float* __restrict__ out) {
    __shared__ float sW2[10000];
    __shared__ float sW3[100];
    __shared__ float red[256];
    int t = threadIdx.x;
    for (int idx = t; idx < 10000; idx += 256) sW2[idx] = W2[idx];
    if (t < 100) sW3[t] = W3[t];
    __syncthreads();
    int nb = t >> 2, q = t & 3;
    int n = blockIdx.x * 64 + nb;
    const float* x1 = X1 + (size_t)n * 128;
    float xr[100];
#pragma unroll
    for (int i = 0; i < 100; i++) xr[i] = x1[i];
    float partial = 0.f;
    for (int jj = 0; jj < 25; jj++) {
        int j = q + jj * 4;
        const float* w2r = sW2 + j * 100;
        float acc2 = 0.f;
#pragma unroll
        for (int i = 0; i < 100; i++) acc2 += w2r[i] * xr[i];
        partial += sW3[j] * (acc2 > 0.f ? acc2 : 0.2f * acc2);
    }
    red[t] = partial;
    __syncthreads();
    if (q == 0) out[n] = red[t] + red[t + 1] + red[t + 2] + red[t + 3];
}

extern "C" void kernel_launch(void* const* d_in, const int* in_sizes, int n_in,
                              void* d_out, int out_size, void* d_ws, size_t ws_size,
                              hipStream_t stream) {
    (void)in_sizes; (void)n_in; (void)out_size; (void)ws_size;
    const int*   dots   = (const int*)d_in[0];
    const float* w_each = (const float*)d_in[1];
    const float* w_not  = (const float*)d_in[2];
    const float* w_not2 = (const float*)d_in[3];
    const float* w_emp  = (const float*)d_in[4];
    const float* W1 = (const float*)d_in[5];
    const float* W2 = (const float*)d_in[6];
    const float* W3 = (const float*)d_in[7];
    float* out = (float*)d_out;

    char* ws = (char*)d_ws;
    size_t off = 0;
    auto alloc = [&](size_t bytes) -> char* {
        char* p = ws + off;
        off += (bytes + 255) & ~(size_t)255;
        return p;
    };
    f16* Me    = (f16*)alloc((size_t)PIX * PIX * 2);
    f16* Mn    = (f16*)alloc((size_t)PIX * PIX * 2);
    f16* Mn2   = (f16*)alloc((size_t)PIX * PIX * 2);
    f16* Mem   = (f16*)alloc((size_t)PIX * PIX * 2);
    f16* W1b   = (f16*)alloc((size_t)128 * PIX * 2);
    unsigned char* board = (unsigned char*)alloc((size_t)NB * PIX);
    f16* NC    = (f16*)alloc((size_t)MR * PIX * 2);
    f16* En    = (f16*)alloc((size_t)NB * PIX * 2);
    f16* S1sel = (f16*)alloc((size_t)NB * PIX * 2);
    f16* Sa    = (f16*)alloc((size_t)NB * PIX * 2);
    f16* Sb    = (f16*)alloc((size_t)NB * PIX * 2);
    f16* feat  = (f16*)alloc((size_t)NB * PIX * 2);
    f16* Lsel  = (f16*)alloc((size_t)NB * PIX * 2);
    float* X1  = (float*)alloc((size_t)NB * 128 * 4);

    build_board<<<1024, 256, 0, stream>>>(dots, board);
    build_mats<<<4096, 256, 0, stream>>>(w_each, w_not, w_not2, w_emp,
                                         Me, Mn, Mn2, Mem);
    build_w1<<<512, 256, 0, stream>>>(W1, W1b);

    dim3 blk(256);
    // Phase A: stage1-sel + NC + En, one dispatch
    gemm_fa<<<2304, blk, 0, stream>>>(Me, Mn, Mem, board, S1sel, NC, En);
    // L0 / s0
    mk_sa<<<16384, blk, 0, stream>>>(S1sel, En, NC, board, Lsel, Sa);
    // depth 1..3 (pipelined)
    gemm_depth<3><<<1024, blk, 0, stream>>>(Mn2, board, NC, Sa, En, Lsel, Sb);
    gemm_depth<3><<<1024, blk, 0, stream>>>(Mn2, board, NC, Sb, En, Lsel, Sa);
    gemm_depth<3><<<1024, blk, 0, stream>>>(Mn2, board, NC, Sa, En, Lsel, Sb);
    // depth 4 -> feat
    gemm_depth<4><<<1024, blk, 0, stream>>>(Mn2, board, NC, Sb, En, Lsel, feat);
    // MLP
    gemm_mlp<<<32, blk, 0, stream>>>(feat, W1b, X1);
    mlp23<<<64, blk, 0, stream>>>(X1, W2, W3, out);
}

// Round 9
// 426.918 us; speedup vs baseline: 1.0596x; 1.0596x over previous
//
#include <hip/hip_runtime.h>
#include <cstdint>
#include <cstddef>

// ---------------------------------------------------------------------------
// NN_each_LN_exp: 33x33 SAME convs on 32x32 maps = dense 1024x1024 linear
// operators -> f16 MFMA GEMMs with fused epilogues. Row layout r = n*4+k:
// the 16x16x32 MFMA acc quad holds all 4 colors of one (n,o) cell.
// R9: best-of assembly. Depth = exact R2 config (sync NC*s staging,
// launch_bounds(256,2), 32KB LDS, acc[4][4]) -- measured 59us across R2;
// (256,4) cost +15us (R7), explicit prefetch +21us (R8). Phase A = R7's
// fused stage1-sel/NC/En dispatch (101us measured).
// ---------------------------------------------------------------------------

typedef _Float16 f16;
typedef __attribute__((ext_vector_type(8))) _Float16 f16x8;
typedef __attribute__((ext_vector_type(4))) float f32x4;

#define NB   4096
#define PIX  1024
#define MR   (NB * 4)

__device__ __forceinline__ void gld_lds16(const void* g, void* l) {
    __builtin_amdgcn_global_load_lds(
        (const __attribute__((address_space(1))) void*)g,
        (__attribute__((address_space(3))) void*)l, 16, 0, 0);
}

// Conv matrices (1024x1024 f16): M[o][in] = w[a-i+16][b-j+16]
__global__ void build_mats(const float* __restrict__ we, const float* __restrict__ wn,
                           const float* __restrict__ wn2, const float* __restrict__ wem,
                           f16* __restrict__ Me, f16* __restrict__ Mn,
                           f16* __restrict__ Mn2, f16* __restrict__ Mem) {
    int idx = blockIdx.x * 256 + threadIdx.x;
    int o = idx >> 10, in = idx & 1023;
    int i = o >> 5, j = o & 31, a = in >> 5, b = in & 31;
    int u = a - i + 16, v = b - j + 16;
    bool ok = (u >= 0) && (u < 33) && (v >= 0) && (v < 33);
    int w = u * 33 + v;
    float ve = 0.f, vn = 0.f, vn2 = 0.f, vem = 0.f;
    if (ok) { ve = we[w]; vn = wn[w]; vn2 = wn2[w]; vem = wem[w]; }
    Me[idx]  = (f16)ve;
    Mn[idx]  = (f16)vn;
    Mn2[idx] = (f16)vn2;
    Mem[idx] = (f16)vem;
}

// W1 (100,1024) fp32 -> padded (128,1024) f16
__global__ void build_w1(const float* __restrict__ W1, f16* __restrict__ W1b) {
    int idx = blockIdx.x * 256 + threadIdx.x;
    int j = idx >> 10, i = idx & 1023;
    W1b[idx] = (f16)(j < 100 ? W1[j * 1024 + i] : 0.f);
}

// dots (34,32,4096) int32, (v,h,b) -> board[n*1024+p] bytes, LDS transpose
__global__ void build_board(const int* __restrict__ dots, unsigned char* __restrict__ board) {
    __shared__ unsigned char tile[64][68];
    int t = threadIdx.x;
    int bp = blockIdx.x & 15, bn = blockIdx.x >> 4;
    int p0 = bp * 64, n0 = bn * 64;
    int ln = t & 63, lp = t >> 6;
#pragma unroll
    for (int j = 0; j < 16; j++) {
        int p = lp * 16 + j;
        tile[p][ln] = (unsigned char)dots[(size_t)(p0 + p) * 4096 + n0 + ln];
    }
    __syncthreads();
#pragma unroll
    for (int j = 0; j < 16; j++) {
        int n = lp * 16 + j;
        board[(size_t)(n0 + n) * 1024 + p0 + ln] = tile[ln][n];
    }
}

// L0 = S1sel + En - NC_sel (gather); Sa = sigmoid(L0)
__global__ void mk_sa(const f16* __restrict__ S1sel, const f16* __restrict__ En,
                      const f16* __restrict__ NC,
                      const unsigned char* __restrict__ board,
                      float* __restrict__ Lsel, f16* __restrict__ Sa) {
    int idx = blockIdx.x * 256 + threadIdx.x;      // n*1024+o
    int n = idx >> 10, o = idx & 1023;
    int c = board[idx];
    float L = 0.f;
    if (c > 0) {
        float ncsel = (float)NC[(size_t)(4 * n + c - 1) * 1024 + o];
        L = (float)S1sel[idx] + (float)En[idx] - ncsel;
    }
    Lsel[idx] = L;
    Sa[idx] = (f16)(1.f / (1.f + __expf(-L)));
}

// ---------------------------------------------------------------------------
// Core GEMM: C(M x N) = A(M x 1024) * B(N x 1024)^T, f16 in, f32 acc.
// BM=BN=128, BK=64, 4 waves as 2x2 (wave tile 64x64), 16x16x32 MFMA,
// XOR-swizzled chunks (R2-verified conflict-free).
// ASRC: 0 direct async   1 NC*s sync-staged (R2 pattern)
//       2 each(board)    3 notm(board)    4 empty(board)   [frag-time expand]
// MODE: 0 f16-out ldo    1 S1sel-select   3 depth   4 depth-final   5 f32 leaky
// ---------------------------------------------------------------------------
template <int MODE, int ASRC>
__device__ __forceinline__ void run_gemm(
    int bjob, int ypx, int nx, char* smem,
    const f16* __restrict__ X, const f16* __restrict__ B,
    const unsigned char* __restrict__ board, const f16* __restrict__ NCs,
    const f16* __restrict__ Sin, const f16* __restrict__ En,
    float* __restrict__ Lsel, f16* __restrict__ outB, int ldo,
    float* __restrict__ outF) {
    char* smB = smem;                              // 16 KB
    char* smA = smem + 16384;

    const int tid = threadIdx.x;
    const int wv = tid >> 6, ln = tid & 63;
    const int wm = wv >> 1, wn_ = wv & 1;
    const int lr = ln & 15, lq = ln >> 4;

    int xcd = bjob & 7, slot = bjob >> 3;
    int bx = slot % nx;
    int by = xcd * ypx + slot / nx;
    const int rtile = by * 128, otile = bx * 128;
    const int img0 = (ASRC == 4) ? rtile : (rtile >> 2);

    const f32x4 fz = {0.f, 0.f, 0.f, 0.f};
    f32x4 acc[4][4];
#pragma unroll
    for (int i = 0; i < 4; i++)
#pragma unroll
        for (int j = 0; j < 4; j++) acc[i][j] = fz;

    for (int kb = 0; kb < 1024; kb += 64) {
        // ---- staging ----
#pragma unroll
        for (int t = 0; t < 4; t++) {              // B: async
            int c = (wv * 4 + t) * 64 + ln;
            int row = c >> 3, gcol = (c & 7) ^ (row & 7);
            gld_lds16(B + (size_t)(otile + row) * 1024 + kb + gcol * 8, smB + c * 16);
        }
        if (ASRC == 0) {
#pragma unroll
            for (int t = 0; t < 4; t++) {
                int c = (wv * 4 + t) * 64 + ln;
                int row = c >> 3, gcol = (c & 7) ^ (row & 7);
                gld_lds16(X + (size_t)(rtile + row) * 1024 + kb + gcol * 8, smA + c * 16);
            }
        } else if (ASRC == 1) {                    // NC*s product, sync (R2)
#pragma unroll
            for (int t = 0; t < 4; t++) {
                int c = (wv * 4 + t) * 64 + ln;
                int row = c >> 3, gcol = (c & 7) ^ (row & 7);
                int gr = rtile + row;
                f16x8 nc = *(const f16x8*)(NCs + (size_t)gr * 1024 + kb + gcol * 8);
                f16x8 sv = *(const f16x8*)(Sin + (size_t)(gr >> 2) * 1024 + kb + gcol * 8);
                *(f16x8*)(smA + c * 16) = nc * sv;
            }
        } else if (ASRC == 4) {                    // board: 128 maps = 512 slots
#pragma unroll
            for (int t = 0; t < 2; t++) {
                int c = t * 256 + wv * 64 + ln;
                int row = c >> 2, g = (c & 3) ^ (row & 3);
                gld_lds16(board + (size_t)(img0 + row) * 1024 + kb + g * 16, smA + c * 16);
            }
        } else {                                   // ASRC 2/3: 32 maps = 128 slots
            if (wv < 2) {
                int c = wv * 64 + ln;
                int row = c >> 2, g = (c & 3) ^ (row & 3);
                gld_lds16(board + (size_t)(img0 + row) * 1024 + kb + g * 16, smA + c * 16);
            }
        }
        __syncthreads();

        // ---- compute: 2 kk, oct = kk*4+lq in 0..7 ----
#pragma unroll
        for (int kk = 0; kk < 2; kk++) {
            const int oct = kk * 4 + lq;
            f16x8 af[4], bfr[4];
#pragma unroll
            for (int i = 0; i < 4; i++) {
                int rrow = wm * 64 + i * 16 + lr;
                if (ASRC == 0 || ASRC == 1) {
                    af[i] = *(const f16x8*)(smA + rrow * 128 + (oct ^ (rrow & 7)) * 16);
                } else {
                    int m = (ASRC == 4) ? rrow : (rrow >> 2);
                    int k1 = (rrow & 3) + 1;
                    uint64_t bb = *(const uint64_t*)(smA + m * 64 +
                                    ((oct >> 1) ^ (m & 3)) * 16 + (oct & 1) * 8);
                    f16x8 v;
#pragma unroll
                    for (int jj = 0; jj < 8; jj++) {
                        int bj = (int)((bb >> (8 * jj)) & 0xff);
                        bool on = (ASRC == 2) ? (bj == k1)
                                : (ASRC == 3) ? (bj != 0 && bj != k1)
                                              : (bj == 0);
                        v[jj] = on ? (f16)1.f : (f16)0.f;
                    }
                    af[i] = v;
                }
            }
#pragma unroll
            for (int j = 0; j < 4; j++) {
                int brow = wn_ * 64 + j * 16 + lr;
                bfr[j] = *(const f16x8*)(smB + brow * 128 + (oct ^ (brow & 7)) * 16);
            }
#pragma unroll
            for (int i = 0; i < 4; i++)
#pragma unroll
                for (int j = 0; j < 4; j++)
                    acc[i][j] = __builtin_amdgcn_mfma_f32_16x16x32_f16(
                        af[i], bfr[j], acc[i][j], 0, 0, 0);
        }
        __syncthreads();
    }

    // ---- epilogue ----
#pragma unroll
    for (int i = 0; i < 4; i++) {
        int rbase = rtile + wm * 64 + i * 16 + lq * 4;
#pragma unroll
        for (int j = 0; j < 4; j++) {
            int o = otile + wn_ * 64 + j * 16 + lr;
            f32x4 a = acc[i][j];
            if (MODE == 0) {
#pragma unroll
                for (int v = 0; v < 4; v++)
                    outB[(size_t)(rbase + v) * ldo + o] = (f16)a[v];
            } else if (MODE == 5) {
#pragma unroll
                for (int v = 0; v < 4; v++) {
                    float x = a[v];
                    outF[(size_t)(rbase + v) * ldo + o] = x > 0.f ? x : 0.2f * x;
                }
            } else {                               // 1,3,4: quad = 4 colors, cell n
                int n = rbase >> 2;
                size_t no = (size_t)n * PIX + o;
                int c = board[no];
                float asel = (c == 1) ? a[0] : (c == 2) ? a[1] : (c == 3) ? a[2] : a[3];
                if (MODE == 1) {
                    outB[no] = (f16)asel;          // selected conv_we(each)
                } else {
                    float E = (float)En[no];
                    float Lnew = (c > 0) ? (Lsel[no] + E + asel) : 0.f;
                    float s = 1.f / (1.f + __expf(-Lnew));
                    if (MODE != 4) Lsel[no] = Lnew;
                    outB[no] = (f16)s;
                }
            }
        }
    }
}

// Phase A: [0,1024) stage1-sel, [1024,2048) NC, [2048,2304) En
__global__ void __launch_bounds__(256, 4) gemm_fa(
    const f16* __restrict__ Me, const f16* __restrict__ Mn,
    const f16* __restrict__ Mem, const unsigned char* __restrict__ board,
    f16* __restrict__ S1sel, f16* __restrict__ NC, f16* __restrict__ En) {
    __shared__ __attribute__((aligned(16))) char smem[24576];
    int bi = blockIdx.x;
    if (bi < 1024) {
        run_gemm<1, 2>(bi, 16, 8, smem, nullptr, Me, board, nullptr, nullptr,
                       nullptr, nullptr, S1sel, 0, nullptr);
    } else if (bi < 2048) {
        run_gemm<0, 3>(bi - 1024, 16, 8, smem, nullptr, Mn, board, nullptr, nullptr,
                       nullptr, nullptr, NC, PIX, nullptr);
    } else {
        run_gemm<0, 4>(bi - 2048, 4, 8, smem, nullptr, Mem, board, nullptr, nullptr,
                       nullptr, nullptr, En, PIX, nullptr);
    }
}

// Depth GEMM: exact R2 config — sync NC*s staging, launch_bounds(256,2).
// MODE 3 (update L, write s) / 4 (feat only)
template <int MODE>
__global__ void __launch_bounds__(256, 2) gemm_depth(
    const f16* __restrict__ Mn2, const unsigned char* __restrict__ board,
    const f16* __restrict__ NCs, const f16* __restrict__ Sin,
    const f16* __restrict__ En, float* __restrict__ Lsel,
    f16* __restrict__ outB) {
    __shared__ __attribute__((aligned(16))) char smem[32768];
    run_gemm<MODE, 1>(blockIdx.x, 16, 8, smem, nullptr, Mn2, board, NCs,
                      Sin, En, Lsel, outB, 0, nullptr);
}

// MLP layer 1: X1 = leaky(feat @ W1b^T), N=128
__global__ void __launch_bounds__(256, 4) gemm_mlp(
    const f16* __restrict__ feat, const f16* __restrict__ W1b,
    float* __restrict__ X1) {
    __shared__ __attribute__((aligned(16))) char smem[32768];
    run_gemm<5, 0>(blockIdx.x, 4, 1, smem, feat, W1b, nullptr, nullptr,
                   nullptr, nullptr, nullptr, nullptr, 128, X1);
}

// MLP layers 2+3
__global__ void __launch_bounds__(256) mlp23(const float* __restrict__ X1,
                                             const float* __restrict__ W2,
                                             const float* __restrict__ W3,
                                             float* __restrict__ out) {
    __shared__ float sW2[10000];
    __shared__ float sW3[100];
    __shared__ float red[256];
    int t = threadIdx.x;
    for (int idx = t; idx < 10000; idx += 256) sW2[idx] = W2[idx];
    if (t < 100) sW3[t] = W3[t];
    __syncthreads();
    int nb = t >> 2, q = t & 3;
    int n = blockIdx.x * 64 + nb;
    const float* x1 = X1 + (size_t)n * 128;
    float xr[100];
#pragma unroll
    for (int i = 0; i < 100; i++) xr[i] = x1[i];
    float partial = 0.f;
    for (int jj = 0; jj < 25; jj++) {
        int j = q + jj * 4;
        const float* w2r = sW2 + j * 100;
        float acc2 = 0.f;
#pragma unroll
        for (int i = 0; i < 100; i++) acc2 += w2r[i] * xr[i];
        partial += sW3[j] * (acc2 > 0.f ? acc2 : 0.2f * acc2);
    }
    red[t] = partial;
    __syncthreads();
    if (q == 0) out[n] = red[t] + red[t + 1] + red[t + 2] + red[t + 3];
}

extern "C" void kernel_launch(void* const* d_in, const int* in_sizes, int n_in,
                              void* d_out, int out_size, void* d_ws, size_t ws_size,
                              hipStream_t stream) {
    (void)in_sizes; (void)n_in; (void)out_size; (void)ws_size;
    const int*   dots   = (const int*)d_in[0];
    const float* w_each = (const float*)d_in[1];
    const float* w_not  = (const float*)d_in[2];
    const float* w_not2 = (const float*)d_in[3];
    const float* w_emp  = (const float*)d_in[4];
    const float* W1 = (const float*)d_in[5];
    const float* W2 = (const float*)d_in[6];
    const float* W3 = (const float*)d_in[7];
    float* out = (float*)d_out;

    char* ws = (char*)d_ws;
    size_t off = 0;
    auto alloc = [&](size_t bytes) -> char* {
        char* p = ws + off;
        off += (bytes + 255) & ~(size_t)255;
        return p;
    };
    f16* Me    = (f16*)alloc((size_t)PIX * PIX * 2);
    f16* Mn    = (f16*)alloc((size_t)PIX * PIX * 2);
    f16* Mn2   = (f16*)alloc((size_t)PIX * PIX * 2);
    f16* Mem   = (f16*)alloc((size_t)PIX * PIX * 2);
    f16* W1b   = (f16*)alloc((size_t)128 * PIX * 2);
    unsigned char* board = (unsigned char*)alloc((size_t)NB * PIX);
    f16* NC    = (f16*)alloc((size_t)MR * PIX * 2);
    f16* En    = (f16*)alloc((size_t)NB * PIX * 2);
    f16* S1sel = (f16*)alloc((size_t)NB * PIX * 2);
    f16* Sa    = (f16*)alloc((size_t)NB * PIX * 2);
    f16* Sb    = (f16*)alloc((size_t)NB * PIX * 2);
    f16* feat  = (f16*)alloc((size_t)NB * PIX * 2);
    float* Lsel= (float*)alloc((size_t)NB * PIX * 4);
    float* X1  = (float*)alloc((size_t)NB * 128 * 4);

    build_board<<<1024, 256, 0, stream>>>(dots, board);
    build_mats<<<4096, 256, 0, stream>>>(w_each, w_not, w_not2, w_emp,
                                         Me, Mn, Mn2, Mem);
    build_w1<<<512, 256, 0, stream>>>(W1, W1b);

    dim3 blk(256);
    // Phase A: stage1-sel + NC + En, one dispatch
    gemm_fa<<<2304, blk, 0, stream>>>(Me, Mn, Mem, board, S1sel, NC, En);
    // L0 / s0
    mk_sa<<<16384, blk, 0, stream>>>(S1sel, En, NC, board, Lsel, Sa);
    // depth 1..3 (exact R2 config)
    gemm_depth<3><<<1024, blk, 0, stream>>>(Mn2, board, NC, Sa, En, Lsel, Sb);
    gemm_depth<3><<<1024, blk, 0, stream>>>(Mn2, board, NC, Sb, En, Lsel, Sa);
    gemm_depth<3><<<1024, blk, 0, stream>>>(Mn2, board, NC, Sa, En, Lsel, Sb);
    // depth 4 -> feat
    gemm_depth<4><<<1024, blk, 0, stream>>>(Mn2, board, NC, Sb, En, Lsel, feat);
    // MLP
    gemm_mlp<<<32, blk, 0, stream>>>(feat, W1b, X1);
    mlp23<<<64, blk, 0, stream>>>(X1, W2, W3, out);
}

// Round 10
// 417.859 us; speedup vs baseline: 1.0826x; 1.0217x over previous
//
#include <hip/hip_runtime.h>
#include <cstdint>
#include <cstddef>

// ---------------------------------------------------------------------------
// NN_each_LN_exp: 33x33 SAME convs on 32x32 maps = dense 1024x1024 linear
// operators -> f16 MFMA GEMMs with fused epilogues. Row layout r = n*4+k:
// the 16x16x32 MFMA acc quad holds all 4 colors of one (n,o) cell.
// R10: depth GEMM made PURE-async (m97 structure, measured 874 TF): the
// NC*s product P_d is materialized by the PREVIOUS kernel's epilogue
// (mk_sa for d=1, depth epilogue for d=2..4), removing the sync staging
// chain that pinned depth at ~65-73us across R2/R7/R8/R9.
// ---------------------------------------------------------------------------

typedef _Float16 f16;
typedef __attribute__((ext_vector_type(8))) _Float16 f16x8;
typedef __attribute__((ext_vector_type(4))) float f32x4;

#define NB   4096
#define PIX  1024
#define MR   (NB * 4)

__device__ __forceinline__ void gld_lds16(const void* g, void* l) {
    __builtin_amdgcn_global_load_lds(
        (const __attribute__((address_space(1))) void*)g,
        (__attribute__((address_space(3))) void*)l, 16, 0, 0);
}

// Conv matrices (1024x1024 f16): M[o][in] = w[a-i+16][b-j+16]
__global__ void build_mats(const float* __restrict__ we, const float* __restrict__ wn,
                           const float* __restrict__ wn2, const float* __restrict__ wem,
                           f16* __restrict__ Me, f16* __restrict__ Mn,
                           f16* __restrict__ Mn2, f16* __restrict__ Mem) {
    int idx = blockIdx.x * 256 + threadIdx.x;
    int o = idx >> 10, in = idx & 1023;
    int i = o >> 5, j = o & 31, a = in >> 5, b = in & 31;
    int u = a - i + 16, v = b - j + 16;
    bool ok = (u >= 0) && (u < 33) && (v >= 0) && (v < 33);
    int w = u * 33 + v;
    float ve = 0.f, vn = 0.f, vn2 = 0.f, vem = 0.f;
    if (ok) { ve = we[w]; vn = wn[w]; vn2 = wn2[w]; vem = wem[w]; }
    Me[idx]  = (f16)ve;
    Mn[idx]  = (f16)vn;
    Mn2[idx] = (f16)vn2;
    Mem[idx] = (f16)vem;
}

// W1 (100,1024) fp32 -> padded (128,1024) f16
__global__ void build_w1(const float* __restrict__ W1, f16* __restrict__ W1b) {
    int idx = blockIdx.x * 256 + threadIdx.x;
    int j = idx >> 10, i = idx & 1023;
    W1b[idx] = (f16)(j < 100 ? W1[j * 1024 + i] : 0.f);
}

// dots (34,32,4096) int32, (v,h,b) -> board[n*1024+p] bytes, LDS transpose
__global__ void build_board(const int* __restrict__ dots, unsigned char* __restrict__ board) {
    __shared__ unsigned char tile[64][68];
    int t = threadIdx.x;
    int bp = blockIdx.x & 15, bn = blockIdx.x >> 4;
    int p0 = bp * 64, n0 = bn * 64;
    int ln = t & 63, lp = t >> 6;
#pragma unroll
    for (int j = 0; j < 16; j++) {
        int p = lp * 16 + j;
        tile[p][ln] = (unsigned char)dots[(size_t)(p0 + p) * 4096 + n0 + ln];
    }
    __syncthreads();
#pragma unroll
    for (int j = 0; j < 16; j++) {
        int n = lp * 16 + j;
        board[(size_t)(n0 + n) * 1024 + p0 + ln] = tile[ln][n];
    }
}

// L0 = S1sel + En - NC_sel; P1[4n+k] = NC[4n+k] * sigmoid(L0)
__global__ void mk_sa(const f16* __restrict__ S1sel, const f16* __restrict__ En,
                      const f16* __restrict__ NC,
                      const unsigned char* __restrict__ board,
                      float* __restrict__ Lsel, f16* __restrict__ P1) {
    int idx = blockIdx.x * 256 + threadIdx.x;      // n*1024+o
    int n = idx >> 10, o = idx & 1023;
    int c = board[idx];
    size_t r0 = (size_t)(4 * n) * PIX + o;
    f16 nc0 = NC[r0], nc1 = NC[r0 + PIX], nc2 = NC[r0 + 2 * PIX], nc3 = NC[r0 + 3 * PIX];
    float L = 0.f;
    if (c > 0) {
        float ncsel = (float)((c == 1) ? nc0 : (c == 2) ? nc1 : (c == 3) ? nc2 : nc3);
        L = (float)S1sel[idx] + (float)En[idx] - ncsel;
    }
    Lsel[idx] = L;
    f16 s = (f16)(1.f / (1.f + __expf(-L)));
    P1[r0]           = nc0 * s;
    P1[r0 + PIX]     = nc1 * s;
    P1[r0 + 2 * PIX] = nc2 * s;
    P1[r0 + 3 * PIX] = nc3 * s;
}

// ---------------------------------------------------------------------------
// Generic GEMM body (phase A / MLP) — unchanged from R9.
// ASRC: 0 direct async  2 each(board)  3 notm(board)  4 empty(board)
// MODE: 0 f16-out ldo   1 S1sel-select   5 f32 leaky
// ---------------------------------------------------------------------------
template <int MODE, int ASRC>
__device__ __forceinline__ void run_gemm(
    int bjob, int ypx, int nx, char* smem,
    const f16* __restrict__ X, const f16* __restrict__ B,
    const unsigned char* __restrict__ board,
    f16* __restrict__ outB, int ldo, float* __restrict__ outF) {
    char* smB = smem;                              // 16 KB
    char* smA = smem + 16384;

    const int tid = threadIdx.x;
    const int wv = tid >> 6, ln = tid & 63;
    const int wm = wv >> 1, wn_ = wv & 1;
    const int lr = ln & 15, lq = ln >> 4;

    int xcd = bjob & 7, slot = bjob >> 3;
    int bx = slot % nx;
    int by = xcd * ypx + slot / nx;
    const int rtile = by * 128, otile = bx * 128;
    const int img0 = (ASRC == 4) ? rtile : (rtile >> 2);

    const f32x4 fz = {0.f, 0.f, 0.f, 0.f};
    f32x4 acc[4][4];
#pragma unroll
    for (int i = 0; i < 4; i++)
#pragma unroll
        for (int j = 0; j < 4; j++) acc[i][j] = fz;

    for (int kb = 0; kb < 1024; kb += 64) {
#pragma unroll
        for (int t = 0; t < 4; t++) {              // B: async
            int c = (wv * 4 + t) * 64 + ln;
            int row = c >> 3, gcol = (c & 7) ^ (row & 7);
            gld_lds16(B + (size_t)(otile + row) * 1024 + kb + gcol * 8, smB + c * 16);
        }
        if (ASRC == 0) {
#pragma unroll
            for (int t = 0; t < 4; t++) {
                int c = (wv * 4 + t) * 64 + ln;
                int row = c >> 3, gcol = (c & 7) ^ (row & 7);
                gld_lds16(X + (size_t)(rtile + row) * 1024 + kb + gcol * 8, smA + c * 16);
            }
        } else if (ASRC == 4) {                    // board: 128 maps = 512 slots
#pragma unroll
            for (int t = 0; t < 2; t++) {
                int c = t * 256 + wv * 64 + ln;
                int row = c >> 2, g = (c & 3) ^ (row & 3);
                gld_lds16(board + (size_t)(img0 + row) * 1024 + kb + g * 16, smA + c * 16);
            }
        } else {                                   // ASRC 2/3: 32 maps = 128 slots
            if (wv < 2) {
                int c = wv * 64 + ln;
                int row = c >> 2, g = (c & 3) ^ (row & 3);
                gld_lds16(board + (size_t)(img0 + row) * 1024 + kb + g * 16, smA + c * 16);
            }
        }
        __syncthreads();

#pragma unroll
        for (int kk = 0; kk < 2; kk++) {
            const int oct = kk * 4 + lq;
            f16x8 af[4], bfr[4];
#pragma unroll
            for (int i = 0; i < 4; i++) {
                int rrow = wm * 64 + i * 16 + lr;
                if (ASRC == 0) {
                    af[i] = *(const f16x8*)(smA + rrow * 128 + (oct ^ (rrow & 7)) * 16);
                } else {
                    int m = (ASRC == 4) ? rrow : (rrow >> 2);
                    int k1 = (rrow & 3) + 1;
                    uint64_t bb = *(const uint64_t*)(smA + m * 64 +
                                    ((oct >> 1) ^ (m & 3)) * 16 + (oct & 1) * 8);
                    f16x8 v;
#pragma unroll
                    for (int jj = 0; jj < 8; jj++) {
                        int bj = (int)((bb >> (8 * jj)) & 0xff);
                        bool on = (ASRC == 2) ? (bj == k1)
                                : (ASRC == 3) ? (bj != 0 && bj != k1)
                                              : (bj == 0);
                        v[jj] = on ? (f16)1.f : (f16)0.f;
                    }
                    af[i] = v;
                }
            }
#pragma unroll
            for (int j = 0; j < 4; j++) {
                int brow = wn_ * 64 + j * 16 + lr;
                bfr[j] = *(const f16x8*)(smB + brow * 128 + (oct ^ (brow & 7)) * 16);
            }
#pragma unroll
            for (int i = 0; i < 4; i++)
#pragma unroll
                for (int j = 0; j < 4; j++)
                    acc[i][j] = __builtin_amdgcn_mfma_f32_16x16x32_f16(
                        af[i], bfr[j], acc[i][j], 0, 0, 0);
        }
        __syncthreads();
    }

#pragma unroll
    for (int i = 0; i < 4; i++) {
        int rbase = rtile + wm * 64 + i * 16 + lq * 4;
#pragma unroll
        for (int j = 0; j < 4; j++) {
            int o = otile + wn_ * 64 + j * 16 + lr;
            f32x4 a = acc[i][j];
            if (MODE == 0) {
#pragma unroll
                for (int v = 0; v < 4; v++)
                    outB[(size_t)(rbase + v) * ldo + o] = (f16)a[v];
            } else if (MODE == 5) {
#pragma unroll
                for (int v = 0; v < 4; v++) {
                    float x = a[v];
                    outF[(size_t)(rbase + v) * ldo + o] = x > 0.f ? x : 0.2f * x;
                }
            } else {                               // 1: selected color only
                int n = rbase >> 2;
                size_t no = (size_t)n * PIX + o;
                int c = board[no];
                float asel = (c == 1) ? a[0] : (c == 2) ? a[1] : (c == 3) ? a[2] : a[3];
                outB[no] = (f16)asel;
            }
        }
    }
}

// Phase A: [0,1024) stage1-sel, [1024,2048) NC, [2048,2304) En
__global__ void __launch_bounds__(256, 4) gemm_fa(
    const f16* __restrict__ Me, const f16* __restrict__ Mn,
    const f16* __restrict__ Mem, const unsigned char* __restrict__ board,
    f16* __restrict__ S1sel, f16* __restrict__ NC, f16* __restrict__ En) {
    __shared__ __attribute__((aligned(16))) char smem[24576];
    int bi = blockIdx.x;
    if (bi < 1024) {
        run_gemm<1, 2>(bi, 16, 8, smem, nullptr, Me, board, S1sel, 0, nullptr);
    } else if (bi < 2048) {
        run_gemm<0, 3>(bi - 1024, 16, 8, smem, nullptr, Mn, board, NC, PIX, nullptr);
    } else {
        run_gemm<0, 4>(bi - 2048, 4, 8, smem, nullptr, Mem, board, En, PIX, nullptr);
    }
}

// ---------------------------------------------------------------------------
// Depth GEMM, pure-async (m97 structure): A = P_d, B = Mn2, both via
// global_load_lds. Epilogue: L += E + Csel, s = sigmoid; MODE 3 writes
// Lsel + P_{d+1} = NC * s; MODE 4 writes feat = s only.
// ---------------------------------------------------------------------------
template <int MODE>
__global__ void __launch_bounds__(256, 2) gemm_depth(
    const f16* __restrict__ Pin, const f16* __restrict__ Mn2,
    const unsigned char* __restrict__ board, const f16* __restrict__ NC,
    const f16* __restrict__ En, float* __restrict__ Lsel,
    f16* __restrict__ Pout, f16* __restrict__ feat) {
    __shared__ __attribute__((aligned(16))) char smem[32768];
    char* smB = smem;
    char* smA = smem + 16384;

    const int tid = threadIdx.x;
    const int wv = tid >> 6, ln = tid & 63;
    const int wm = wv >> 1, wn_ = wv & 1;
    const int lr = ln & 15, lq = ln >> 4;

    int bi = blockIdx.x;
    int xcd = bi & 7, slot = bi >> 3;
    int bx = slot & 7;
    int by = xcd * 16 + (slot >> 3);
    const int rtile = by * 128, otile = bx * 128;

    const f32x4 fz = {0.f, 0.f, 0.f, 0.f};
    f32x4 acc[4][4];
#pragma unroll
    for (int i = 0; i < 4; i++)
#pragma unroll
        for (int j = 0; j < 4; j++) acc[i][j] = fz;

    for (int kb = 0; kb < 1024; kb += 64) {
#pragma unroll
        for (int t = 0; t < 4; t++) {
            int c = (wv * 4 + t) * 64 + ln;
            int row = c >> 3, gcol = (c & 7) ^ (row & 7);
            gld_lds16(Mn2 + (size_t)(otile + row) * 1024 + kb + gcol * 8, smB + c * 16);
            gld_lds16(Pin + (size_t)(rtile + row) * 1024 + kb + gcol * 8, smA + c * 16);
        }
        __syncthreads();

#pragma unroll
        for (int kk = 0; kk < 2; kk++) {
            const int oct = kk * 4 + lq;
            f16x8 af[4], bfr[4];
#pragma unroll
            for (int i = 0; i < 4; i++) {
                int rrow = wm * 64 + i * 16 + lr;
                af[i] = *(const f16x8*)(smA + rrow * 128 + (oct ^ (rrow & 7)) * 16);
            }
#pragma unroll
            for (int j = 0; j < 4; j++) {
                int brow = wn_ * 64 + j * 16 + lr;
                bfr[j] = *(const f16x8*)(smB + brow * 128 + (oct ^ (brow & 7)) * 16);
            }
#pragma unroll
            for (int i = 0; i < 4; i++)
#pragma unroll
                for (int j = 0; j < 4; j++)
                    acc[i][j] = __builtin_amdgcn_mfma_f32_16x16x32_f16(
                        af[i], bfr[j], acc[i][j], 0, 0, 0);
        }
        __syncthreads();
    }

    // epilogue: quad = 4 colors of cell n at column o
#pragma unroll
    for (int i = 0; i < 4; i++) {
        int rbase = rtile + wm * 64 + i * 16 + lq * 4;
#pragma unroll
        for (int j = 0; j < 4; j++) {
            int o = otile + wn_ * 64 + j * 16 + lr;
            f32x4 a = acc[i][j];
            int n = rbase >> 2;
            size_t no = (size_t)n * PIX + o;
            int c = board[no];
            float asel = (c == 1) ? a[0] : (c == 2) ? a[1] : (c == 3) ? a[2] : a[3];
            float E = (float)En[no];
            float Lnew = (c > 0) ? (Lsel[no] + E + asel) : 0.f;
            float s = 1.f / (1.f + __expf(-Lnew));
            if (MODE == 4) {
                feat[no] = (f16)s;
            } else {
                Lsel[no] = Lnew;
                f16 sh = (f16)s;
                size_t r0 = (size_t)rbase * PIX + o;
                Pout[r0]           = NC[r0] * sh;
                Pout[r0 + PIX]     = NC[r0 + PIX] * sh;
                Pout[r0 + 2 * PIX] = NC[r0 + 2 * PIX] * sh;
                Pout[r0 + 3 * PIX] = NC[r0 + 3 * PIX] * sh;
            }
        }
    }
}

// MLP layer 1: X1 = leaky(feat @ W1b^T), N=128
__global__ void __launch_bounds__(256, 4) gemm_mlp(
    const f16* __restrict__ feat, const f16* __restrict__ W1b,
    float* __restrict__ X1) {
    __shared__ __attribute__((aligned(16))) char smem[32768];
    run_gemm<5, 0>(blockIdx.x, 4, 1, smem, feat, W1b, nullptr, nullptr, 128, X1);
}

// MLP layers 2+3
__global__ void __launch_bounds__(256) mlp23(const float* __restrict__ X1,
                                             const float* __restrict__ W2,
                                             const float* __restrict__ W3,
                                             float* __restrict__ out) {
    __shared__ float sW2[10000];
    __shared__ float sW3[100];
    __shared__ float red[256];
    int t = threadIdx.x;
    for (int idx = t; idx < 10000; idx += 256) sW2[idx] = W2[idx];
    if (t < 100) sW3[t] = W3[t];
    __syncthreads();
    int nb = t >> 2, q = t & 3;
    int n = blockIdx.x * 64 + nb;
    const float* x1 = X1 + (size_t)n * 128;
    float xr[100];
#pragma unroll
    for (int i = 0; i < 100; i++) xr[i] = x1[i];
    float partial = 0.f;
    for (int jj = 0; jj < 25; jj++) {
        int j = q + jj * 4;
        const float* w2r = sW2 + j * 100;
        float acc2 = 0.f;
#pragma unroll
        for (int i = 0; i < 100; i++) acc2 += w2r[i] * xr[i];
        partial += sW3[j] * (acc2 > 0.f ? acc2 : 0.2f * acc2);
    }
    red[t] = partial;
    __syncthreads();
    if (q == 0) out[n] = red[t] + red[t + 1] + red[t + 2] + red[t + 3];
}

extern "C" void kernel_launch(void* const* d_in, const int* in_sizes, int n_in,
                              void* d_out, int out_size, void* d_ws, size_t ws_size,
                              hipStream_t stream) {
    (void)in_sizes; (void)n_in; (void)out_size; (void)ws_size;
    const int*   dots   = (const int*)d_in[0];
    const float* w_each = (const float*)d_in[1];
    const float* w_not  = (const float*)d_in[2];
    const float* w_not2 = (const float*)d_in[3];
    const float* w_emp  = (const float*)d_in[4];
    const float* W1 = (const float*)d_in[5];
    const float* W2 = (const float*)d_in[6];
    const float* W3 = (const float*)d_in[7];
    float* out = (float*)d_out;

    char* ws = (char*)d_ws;
    size_t off = 0;
    auto alloc = [&](size_t bytes) -> char* {
        char* p = ws + off;
        off += (bytes + 255) & ~(size_t)255;
        return p;
    };
    f16* Me    = (f16*)alloc((size_t)PIX * PIX * 2);
    f16* Mn    = (f16*)alloc((size_t)PIX * PIX * 2);
    f16* Mn2   = (f16*)alloc((size_t)PIX * PIX * 2);
    f16* Mem   = (f16*)alloc((size_t)PIX * PIX * 2);
    f16* W1b   = (f16*)alloc((size_t)128 * PIX * 2);
    unsigned char* board = (unsigned char*)alloc((size_t)NB * PIX);
    f16* NC    = (f16*)alloc((size_t)MR * PIX * 2);
    f16* En    = (f16*)alloc((size_t)NB * PIX * 2);
    f16* S1sel = (f16*)alloc((size_t)NB * PIX * 2);
    f16* Pa    = (f16*)alloc((size_t)MR * PIX * 2);
    f16* Pb    = (f16*)alloc((size_t)MR * PIX * 2);
    f16* feat  = (f16*)alloc((size_t)NB * PIX * 2);
    float* Lsel= (float*)alloc((size_t)NB * PIX * 4);
    float* X1  = (float*)alloc((size_t)NB * 128 * 4);

    build_board<<<1024, 256, 0, stream>>>(dots, board);
    build_mats<<<4096, 256, 0, stream>>>(w_each, w_not, w_not2, w_emp,
                                         Me, Mn, Mn2, Mem);
    build_w1<<<512, 256, 0, stream>>>(W1, W1b);

    dim3 blk(256);
    // Phase A: stage1-sel + NC + En, one dispatch
    gemm_fa<<<2304, blk, 0, stream>>>(Me, Mn, Mem, board, S1sel, NC, En);
    // L0, P1 = NC * sigmoid(L0)
    mk_sa<<<16384, blk, 0, stream>>>(S1sel, En, NC, board, Lsel, Pa);
    // depth 1..3: pure-async GEMM; epilogue emits P_{d+1}
    gemm_depth<3><<<1024, blk, 0, stream>>>(Pa, Mn2, board, NC, En, Lsel, Pb, nullptr);
    gemm_depth<3><<<1024, blk, 0, stream>>>(Pb, Mn2, board, NC, En, Lsel, Pa, nullptr);
    gemm_depth<3><<<1024, blk, 0, stream>>>(Pa, Mn2, board, NC, En, Lsel, Pb, nullptr);
    // depth 4 -> feat
    gemm_depth<4><<<1024, blk, 0, stream>>>(Pb, Mn2, board, NC, En, Lsel, nullptr, feat);
    // MLP
    gemm_mlp<<<32, blk, 0, stream>>>(feat, W1b, X1);
    mlp23<<<64, blk, 0, stream>>>(X1, W2, W3, out);
}

// Round 11
// 410.416 us; speedup vs baseline: 1.1022x; 1.0181x over previous
//
#include <hip/hip_runtime.h>
#include <cstdint>
#include <cstddef>

// ---------------------------------------------------------------------------
// NN_each_LN_exp: 33x33 SAME convs on 32x32 maps = dense 1024x1024 linear
// operators -> f16 MFMA GEMMs with fused epilogues. Row layout r = n*4+k:
// the 16x16x32 MFMA acc quad holds all 4 colors of one (n,o) cell.
// R11 (on R10's 417.9us): Lsel f16 (R8-validated), MLP2+3 fused into the
// MLP1 GEMM epilogue (block holds full 100-dim feature for its 128 batches),
// 3 build kernels merged into 1 dispatch.
// ---------------------------------------------------------------------------

typedef _Float16 f16;
typedef __attribute__((ext_vector_type(8))) _Float16 f16x8;
typedef __attribute__((ext_vector_type(4))) float f32x4;

#define NB   4096
#define PIX  1024
#define MR   (NB * 4)

__device__ __forceinline__ void gld_lds16(const void* g, void* l) {
    __builtin_amdgcn_global_load_lds(
        (const __attribute__((address_space(1))) void*)g,
        (__attribute__((address_space(3))) void*)l, 16, 0, 0);
}

// Merged builds: [0,4096) conv mats, [4096,4608) W1 pad, [4608,5632) board
__global__ void build_all(const float* __restrict__ we, const float* __restrict__ wn,
                          const float* __restrict__ wn2, const float* __restrict__ wem,
                          const float* __restrict__ W1, const int* __restrict__ dots,
                          f16* __restrict__ Me, f16* __restrict__ Mn,
                          f16* __restrict__ Mn2, f16* __restrict__ Mem,
                          f16* __restrict__ W1b, unsigned char* __restrict__ board) {
    __shared__ unsigned char tile[64][68];
    int bi = blockIdx.x, t = threadIdx.x;
    if (bi < 4096) {
        int idx = bi * 256 + t;
        int o = idx >> 10, in = idx & 1023;
        int i = o >> 5, j = o & 31, a = in >> 5, b = in & 31;
        int u = a - i + 16, v = b - j + 16;
        bool ok = (u >= 0) && (u < 33) && (v >= 0) && (v < 33);
        int w = u * 33 + v;
        float ve = 0.f, vn = 0.f, vn2 = 0.f, vem = 0.f;
        if (ok) { ve = we[w]; vn = wn[w]; vn2 = wn2[w]; vem = wem[w]; }
        Me[idx]  = (f16)ve;
        Mn[idx]  = (f16)vn;
        Mn2[idx] = (f16)vn2;
        Mem[idx] = (f16)vem;
    } else if (bi < 4608) {
        int idx = (bi - 4096) * 256 + t;
        int j = idx >> 10, i = idx & 1023;
        W1b[idx] = (f16)(j < 100 ? W1[j * 1024 + i] : 0.f);
    } else {
        int bb = bi - 4608;
        int bp = bb & 15, bn = bb >> 4;
        int p0 = bp * 64, n0 = bn * 64;
        int ln = t & 63, lp = t >> 6;
#pragma unroll
        for (int j = 0; j < 16; j++) {
            int p = lp * 16 + j;
            tile[p][ln] = (unsigned char)dots[(size_t)(p0 + p) * 4096 + n0 + ln];
        }
        __syncthreads();
#pragma unroll
        for (int j = 0; j < 16; j++) {
            int n = lp * 16 + j;
            board[(size_t)(n0 + n) * 1024 + p0 + ln] = tile[ln][n];
        }
    }
}

// L0 = S1sel + En - NC_sel; P1[4n+k] = NC[4n+k] * sigmoid(L0); Lsel f16
__global__ void mk_sa(const f16* __restrict__ S1sel, const f16* __restrict__ En,
                      const f16* __restrict__ NC,
                      const unsigned char* __restrict__ board,
                      f16* __restrict__ Lsel, f16* __restrict__ P1) {
    int idx = blockIdx.x * 256 + threadIdx.x;      // n*1024+o
    int n = idx >> 10, o = idx & 1023;
    int c = board[idx];
    size_t r0 = (size_t)(4 * n) * PIX + o;
    f16 nc0 = NC[r0], nc1 = NC[r0 + PIX], nc2 = NC[r0 + 2 * PIX], nc3 = NC[r0 + 3 * PIX];
    float L = 0.f;
    if (c > 0) {
        float ncsel = (float)((c == 1) ? nc0 : (c == 2) ? nc1 : (c == 3) ? nc2 : nc3);
        L = (float)S1sel[idx] + (float)En[idx] - ncsel;
    }
    Lsel[idx] = (f16)L;
    f16 s = (f16)(1.f / (1.f + __expf(-L)));
    P1[r0]           = nc0 * s;
    P1[r0 + PIX]     = nc1 * s;
    P1[r0 + 2 * PIX] = nc2 * s;
    P1[r0 + 3 * PIX] = nc3 * s;
}

// ---------------------------------------------------------------------------
// Generic GEMM body (phase A): BM=BN=128, BK=64, 4 waves as 2x2, 16x16x32
// MFMA, XOR-swizzled chunks (conflict-free frag reads).
// ASRC: 0 direct async  2 each(board)  3 notm(board)  4 empty(board)
// MODE: 0 f16-out ldo   1 S1sel-select
// ---------------------------------------------------------------------------
template <int MODE, int ASRC>
__device__ __forceinline__ void run_gemm(
    int bjob, int ypx, int nx, char* smem,
    const f16* __restrict__ X, const f16* __restrict__ B,
    const unsigned char* __restrict__ board,
    f16* __restrict__ outB, int ldo) {
    char* smB = smem;                              // 16 KB
    char* smA = smem + 16384;

    const int tid = threadIdx.x;
    const int wv = tid >> 6, ln = tid & 63;
    const int wm = wv >> 1, wn_ = wv & 1;
    const int lr = ln & 15, lq = ln >> 4;

    int xcd = bjob & 7, slot = bjob >> 3;
    int bx = slot % nx;
    int by = xcd * ypx + slot / nx;
    const int rtile = by * 128, otile = bx * 128;
    const int img0 = (ASRC == 4) ? rtile : (rtile >> 2);

    const f32x4 fz = {0.f, 0.f, 0.f, 0.f};
    f32x4 acc[4][4];
#pragma unroll
    for (int i = 0; i < 4; i++)
#pragma unroll
        for (int j = 0; j < 4; j++) acc[i][j] = fz;

    for (int kb = 0; kb < 1024; kb += 64) {
#pragma unroll
        for (int t = 0; t < 4; t++) {              // B: async
            int c = (wv * 4 + t) * 64 + ln;
            int row = c >> 3, gcol = (c & 7) ^ (row & 7);
            gld_lds16(B + (size_t)(otile + row) * 1024 + kb + gcol * 8, smB + c * 16);
        }
        if (ASRC == 0) {
#pragma unroll
            for (int t = 0; t < 4; t++) {
                int c = (wv * 4 + t) * 64 + ln;
                int row = c >> 3, gcol = (c & 7) ^ (row & 7);
                gld_lds16(X + (size_t)(rtile + row) * 1024 + kb + gcol * 8, smA + c * 16);
            }
        } else if (ASRC == 4) {                    // board: 128 maps = 512 slots
#pragma unroll
            for (int t = 0; t < 2; t++) {
                int c = t * 256 + wv * 64 + ln;
                int row = c >> 2, g = (c & 3) ^ (row & 3);
                gld_lds16(board + (size_t)(img0 + row) * 1024 + kb + g * 16, smA + c * 16);
            }
        } else {                                   // ASRC 2/3: 32 maps = 128 slots
            if (wv < 2) {
                int c = wv * 64 + ln;
                int row = c >> 2, g = (c & 3) ^ (row & 3);
                gld_lds16(board + (size_t)(img0 + row) * 1024 + kb + g * 16, smA + c * 16);
            }
        }
        __syncthreads();

#pragma unroll
        for (int kk = 0; kk < 2; kk++) {
            const int oct = kk * 4 + lq;
            f16x8 af[4], bfr[4];
#pragma unroll
            for (int i = 0; i < 4; i++) {
                int rrow = wm * 64 + i * 16 + lr;
                if (ASRC == 0) {
                    af[i] = *(const f16x8*)(smA + rrow * 128 + (oct ^ (rrow & 7)) * 16);
                } else {
                    int m = (ASRC == 4) ? rrow : (rrow >> 2);
                    int k1 = (rrow & 3) + 1;
                    uint64_t bb = *(const uint64_t*)(smA + m * 64 +
                                    ((oct >> 1) ^ (m & 3)) * 16 + (oct & 1) * 8);
                    f16x8 v;
#pragma unroll
                    for (int jj = 0; jj < 8; jj++) {
                        int bj = (int)((bb >> (8 * jj)) & 0xff);
                        bool on = (ASRC == 2) ? (bj == k1)
                                : (ASRC == 3) ? (bj != 0 && bj != k1)
                                              : (bj == 0);
                        v[jj] = on ? (f16)1.f : (f16)0.f;
                    }
                    af[i] = v;
                }
            }
#pragma unroll
            for (int j = 0; j < 4; j++) {
                int brow = wn_ * 64 + j * 16 + lr;
                bfr[j] = *(const f16x8*)(smB + brow * 128 + (oct ^ (brow & 7)) * 16);
            }
#pragma unroll
            for (int i = 0; i < 4; i++)
#pragma unroll
                for (int j = 0; j < 4; j++)
                    acc[i][j] = __builtin_amdgcn_mfma_f32_16x16x32_f16(
                        af[i], bfr[j], acc[i][j], 0, 0, 0);
        }
        __syncthreads();
    }

#pragma unroll
    for (int i = 0; i < 4; i++) {
        int rbase = rtile + wm * 64 + i * 16 + lq * 4;
#pragma unroll
        for (int j = 0; j < 4; j++) {
            int o = otile + wn_ * 64 + j * 16 + lr;
            f32x4 a = acc[i][j];
            if (MODE == 0) {
#pragma unroll
                for (int v = 0; v < 4; v++)
                    outB[(size_t)(rbase + v) * ldo + o] = (f16)a[v];
            } else {                               // 1: selected color only
                int n = rbase >> 2;
                size_t no = (size_t)n * PIX + o;
                int c = board[no];
                float asel = (c == 1) ? a[0] : (c == 2) ? a[1] : (c == 3) ? a[2] : a[3];
                outB[no] = (f16)asel;
            }
        }
    }
}

// Phase A: [0,1024) stage1-sel, [1024,2048) NC, [2048,2304) En
__global__ void __launch_bounds__(256, 4) gemm_fa(
    const f16* __restrict__ Me, const f16* __restrict__ Mn,
    const f16* __restrict__ Mem, const unsigned char* __restrict__ board,
    f16* __restrict__ S1sel, f16* __restrict__ NC, f16* __restrict__ En) {
    __shared__ __attribute__((aligned(16))) char smem[24576];
    int bi = blockIdx.x;
    if (bi < 1024) {
        run_gemm<1, 2>(bi, 16, 8, smem, nullptr, Me, board, S1sel, 0);
    } else if (bi < 2048) {
        run_gemm<0, 3>(bi - 1024, 16, 8, smem, nullptr, Mn, board, NC, PIX);
    } else {
        run_gemm<0, 4>(bi - 2048, 4, 8, smem, nullptr, Mem, board, En, PIX);
    }
}

// ---------------------------------------------------------------------------
// Depth GEMM, pure-async (m97 structure): A = P_d, B = Mn2, both via
// global_load_lds. Epilogue: L += E + Csel, s = sigmoid; MODE 3 writes
// Lsel(f16) + P_{d+1} = NC * s; MODE 4 writes feat = s only.
// ---------------------------------------------------------------------------
template <int MODE>
__global__ void __launch_bounds__(256, 2) gemm_depth(
    const f16* __restrict__ Pin, const f16* __restrict__ Mn2,
    const unsigned char* __restrict__ board, const f16* __restrict__ NC,
    const f16* __restrict__ En, f16* __restrict__ Lsel,
    f16* __restrict__ Pout, f16* __restrict__ feat) {
    __shared__ __attribute__((aligned(16))) char smem[32768];
    char* smB = smem;
    char* smA = smem + 16384;

    const int tid = threadIdx.x;
    const int wv = tid >> 6, ln = tid & 63;
    const int wm = wv >> 1, wn_ = wv & 1;
    const int lr = ln & 15, lq = ln >> 4;

    int bi = blockIdx.x;
    int xcd = bi & 7, slot = bi >> 3;
    int bx = slot & 7;
    int by = xcd * 16 + (slot >> 3);
    const int rtile = by * 128, otile = bx * 128;

    const f32x4 fz = {0.f, 0.f, 0.f, 0.f};
    f32x4 acc[4][4];
#pragma unroll
    for (int i = 0; i < 4; i++)
#pragma unroll
        for (int j = 0; j < 4; j++) acc[i][j] = fz;

    for (int kb = 0; kb < 1024; kb += 64) {
#pragma unroll
        for (int t = 0; t < 4; t++) {
            int c = (wv * 4 + t) * 64 + ln;
            int row = c >> 3, gcol = (c & 7) ^ (row & 7);
            gld_lds16(Mn2 + (size_t)(otile + row) * 1024 + kb + gcol * 8, smB + c * 16);
            gld_lds16(Pin + (size_t)(rtile + row) * 1024 + kb + gcol * 8, smA + c * 16);
        }
        __syncthreads();

#pragma unroll
        for (int kk = 0; kk < 2; kk++) {
            const int oct = kk * 4 + lq;
            f16x8 af[4], bfr[4];
#pragma unroll
            for (int i = 0; i < 4; i++) {
                int rrow = wm * 64 + i * 16 + lr;
                af[i] = *(const f16x8*)(smA + rrow * 128 + (oct ^ (rrow & 7)) * 16);
            }
#pragma unroll
            for (int j = 0; j < 4; j++) {
                int brow = wn_ * 64 + j * 16 + lr;
                bfr[j] = *(const f16x8*)(smB + brow * 128 + (oct ^ (brow & 7)) * 16);
            }
#pragma unroll
            for (int i = 0; i < 4; i++)
#pragma unroll
                for (int j = 0; j < 4; j++)
                    acc[i][j] = __builtin_amdgcn_mfma_f32_16x16x32_f16(
                        af[i], bfr[j], acc[i][j], 0, 0, 0);
        }
        __syncthreads();
    }

    // epilogue: quad = 4 colors of cell n at column o
#pragma unroll
    for (int i = 0; i < 4; i++) {
        int rbase = rtile + wm * 64 + i * 16 + lq * 4;
#pragma unroll
        for (int j = 0; j < 4; j++) {
            int o = otile + wn_ * 64 + j * 16 + lr;
            f32x4 a = acc[i][j];
            int n = rbase >> 2;
            size_t no = (size_t)n * PIX + o;
            int c = board[no];
            float asel = (c == 1) ? a[0] : (c == 2) ? a[1] : (c == 3) ? a[2] : a[3];
            float E = (float)En[no];
            float Lnew = (c > 0) ? ((float)Lsel[no] + E + asel) : 0.f;
            float s = 1.f / (1.f + __expf(-Lnew));
            if (MODE == 4) {
                feat[no] = (f16)s;
            } else {
                Lsel[no] = (f16)Lnew;
                f16 sh = (f16)s;
                size_t r0 = (size_t)rbase * PIX + o;
                Pout[r0]           = NC[r0] * sh;
                Pout[r0 + PIX]     = NC[r0 + PIX] * sh;
                Pout[r0 + 2 * PIX] = NC[r0 + 2 * PIX] * sh;
                Pout[r0 + 3 * PIX] = NC[r0 + 3 * PIX] * sh;
            }
        }
    }
}

// ---------------------------------------------------------------------------
// MLP: X1 = leaky(feat @ W1b^T) computed per 128-batch block (N=128 covers
// all 100 features), then layers 2+3 fused in-block via LDS (two 64-batch
// passes; xs stride 101 for bank spread; W2 in f16).
// ---------------------------------------------------------------------------
__global__ void __launch_bounds__(256) gemm_mlp_fused(
    const f16* __restrict__ feat, const f16* __restrict__ W1b,
    const float* __restrict__ W2, const float* __restrict__ W3,
    float* __restrict__ out) {
    __shared__ __attribute__((aligned(16))) char smem[47360];
    char* smB = smem;
    char* smA = smem + 16384;

    const int tid = threadIdx.x;
    const int wv = tid >> 6, ln = tid & 63;
    const int wm = wv >> 1, wn_ = wv & 1;
    const int lr = ln & 15, lq = ln >> 4;
    const int rtile = blockIdx.x * 128;            // 32 blocks

    const f32x4 fz = {0.f, 0.f, 0.f, 0.f};
    f32x4 acc[4][4];
#pragma unroll
    for (int i = 0; i < 4; i++)
#pragma unroll
        for (int j = 0; j < 4; j++) acc[i][j] = fz;

    for (int kb = 0; kb < 1024; kb += 64) {
#pragma unroll
        for (int t = 0; t < 4; t++) {
            int c = (wv * 4 + t) * 64 + ln;
            int row = c >> 3, gcol = (c & 7) ^ (row & 7);
            gld_lds16(W1b  + (size_t)row * 1024 + kb + gcol * 8, smB + c * 16);
            gld_lds16(feat + (size_t)(rtile + row) * 1024 + kb + gcol * 8, smA + c * 16);
        }
        __syncthreads();
#pragma unroll
        for (int kk = 0; kk < 2; kk++) {
            const int oct = kk * 4 + lq;
            f16x8 af[4], bfr[4];
#pragma unroll
            for (int i = 0; i < 4; i++) {
                int rrow = wm * 64 + i * 16 + lr;
                af[i] = *(const f16x8*)(smA + rrow * 128 + (oct ^ (rrow & 7)) * 16);
            }
#pragma unroll
            for (int j = 0; j < 4; j++) {
                int brow = wn_ * 64 + j * 16 + lr;
                bfr[j] = *(const f16x8*)(smB + brow * 128 + (oct ^ (brow & 7)) * 16);
            }
#pragma unroll
            for (int i = 0; i < 4; i++)
#pragma unroll
                for (int j = 0; j < 4; j++)
                    acc[i][j] = __builtin_amdgcn_mfma_f32_16x16x32_f16(
                        af[i], bfr[j], acc[i][j], 0, 0, 0);
        }
        __syncthreads();
    }

    // ---- fused layers 2+3 ----
    float* xs  = (float*)smem;                     // [64][101]
    f16*   sW2 = (f16*)(smem + 25856);             // [100][100]
    float* sW3 = (float*)(smem + 45856);           // [100]
    float* red = (float*)(smem + 46272);           // [256]
    for (int idx = tid; idx < 10000; idx += 256) sW2[idx] = (f16)W2[idx];
    if (tid < 100) sW3[tid] = W3[tid];

    for (int half = 0; half < 2; half++) {
        if (wm == half) {                          // stash leaky(x1) to LDS
#pragma unroll
            for (int i = 0; i < 4; i++) {
                int rb = i * 16 + lq * 4;          // local 0..63
#pragma unroll
                for (int j = 0; j < 4; j++) {
                    int o = wn_ * 64 + j * 16 + lr;
                    if (o < 100) {
                        f32x4 a = acc[i][j];
#pragma unroll
                        for (int v = 0; v < 4; v++) {
                            float x = a[v];
                            xs[(rb + v) * 101 + o] = x > 0.f ? x : 0.2f * x;
                        }
                    }
                }
            }
        }
        __syncthreads();
        int nb = tid >> 2, q = tid & 3;
        const float* xrow = xs + nb * 101;
        float partial = 0.f;
        for (int jj = 0; jj < 25; jj++) {
            int j = q + jj * 4;
            const f16* w2r = sW2 + j * 100;
            float a2 = 0.f;
#pragma unroll
            for (int i = 0; i < 100; i++) a2 += (float)w2r[i] * xrow[i];
            partial += sW3[j] * (a2 > 0.f ? a2 : 0.2f * a2);
        }
        red[tid] = partial;
        __syncthreads();
        if (q == 0)
            out[rtile + half * 64 + nb] = red[tid] + red[tid + 1] + red[tid + 2] + red[tid + 3];
        __syncthreads();
    }
}

extern "C" void kernel_launch(void* const* d_in, const int* in_sizes, int n_in,
                              void* d_out, int out_size, void* d_ws, size_t ws_size,
                              hipStream_t stream) {
    (void)in_sizes; (void)n_in; (void)out_size; (void)ws_size;
    const int*   dots   = (const int*)d_in[0];
    const float* w_each = (const float*)d_in[1];
    const float* w_not  = (const float*)d_in[2];
    const float* w_not2 = (const float*)d_in[3];
    const float* w_emp  = (const float*)d_in[4];
    const float* W1 = (const float*)d_in[5];
    const float* W2 = (const float*)d_in[6];
    const float* W3 = (const float*)d_in[7];
    float* out = (float*)d_out;

    char* ws = (char*)d_ws;
    size_t off = 0;
    auto alloc = [&](size_t bytes) -> char* {
        char* p = ws + off;
        off += (bytes + 255) & ~(size_t)255;
        return p;
    };
    f16* Me    = (f16*)alloc((size_t)PIX * PIX * 2);
    f16* Mn    = (f16*)alloc((size_t)PIX * PIX * 2);
    f16* Mn2   = (f16*)alloc((size_t)PIX * PIX * 2);
    f16* Mem   = (f16*)alloc((size_t)PIX * PIX * 2);
    f16* W1b   = (f16*)alloc((size_t)128 * PIX * 2);
    unsigned char* board = (unsigned char*)alloc((size_t)NB * PIX);
    f16* NC    = (f16*)alloc((size_t)MR * PIX * 2);
    f16* En    = (f16*)alloc((size_t)NB * PIX * 2);
    f16* S1sel = (f16*)alloc((size_t)NB * PIX * 2);
    f16* Pa    = (f16*)alloc((size_t)MR * PIX * 2);
    f16* Pb    = (f16*)alloc((size_t)MR * PIX * 2);
    f16* feat  = (f16*)alloc((size_t)NB * PIX * 2);
    f16* Lsel  = (f16*)alloc((size_t)NB * PIX * 2);

    dim3 blk(256);
    // all precompute in one dispatch
    build_all<<<5632, blk, 0, stream>>>(w_each, w_not, w_not2, w_emp, W1, dots,
                                        Me, Mn, Mn2, Mem, W1b, board);
    // Phase A: stage1-sel + NC + En, one dispatch
    gemm_fa<<<2304, blk, 0, stream>>>(Me, Mn, Mem, board, S1sel, NC, En);
    // L0, P1 = NC * sigmoid(L0)
    mk_sa<<<16384, blk, 0, stream>>>(S1sel, En, NC, board, Lsel, Pa);
    // depth 1..3: pure-async GEMM; epilogue emits P_{d+1}
    gemm_depth<3><<<1024, blk, 0, stream>>>(Pa, Mn2, board, NC, En, Lsel, Pb, nullptr);
    gemm_depth<3><<<1024, blk, 0, stream>>>(Pb, Mn2, board, NC, En, Lsel, Pa, nullptr);
    gemm_depth<3><<<1024, blk, 0, stream>>>(Pa, Mn2, board, NC, En, Lsel, Pb, nullptr);
    // depth 4 -> feat
    gemm_depth<4><<<1024, blk, 0, stream>>>(Pb, Mn2, board, NC, En, Lsel, nullptr, feat);
    // MLP 1+2+3 fused
    gemm_mlp_fused<<<32, blk, 0, stream>>>(feat, W1b, W2, W3, out);
}